// Round 9
// baseline (211.115 us; speedup 1.0000x reference)
//
#include <hip/hip_runtime.h>

// MinVarianceWeightsLayer: for each of B SPD 64x64 fp32 matrices S,
// solve S z = 1, output w = z / sum(z) as [B, 64, 1] fp32.
//
// ROUND-9: rank-4 panel GAUSS-JORDAN. r8's rank-4 panel structure, with the
// elimination gate changed from (lane > k) to (lane != k). The rank-4
// trailing pass was already ungated per-element (SIMT runs all lanes), so
// Jordan costs ZERO extra fma -- and the entire 64-step serial back-sub
// (128 readlanes + 64-deep b-dependency chain) disappears: after 64 steps
// the system is diagonal, z_i = b_i / d_i. Numerics of the Jordan recurrence
// validated in r6 (passed, absmax 2.4e-4). Trailing symmetry (basis of the
// column==row publish) is a property of rows >= k and is unaffected by the
// extra upper-row updates. Diagonals freeze after their own step (updates
// touch columns > k only); captured via one cndmask per pivot.
// One wave per matrix, NO barriers (DS ops in-order within a wave).

#define NN 64

typedef float v2f __attribute__((ext_vector_type(2)));
typedef float v4f __attribute__((ext_vector_type(4)));

template <int I> struct ic { static constexpr int value = I; };

template <int Start, int End, typename F>
__device__ __forceinline__ void static_for(F&& f) {
    if constexpr (Start < End) {
        f(ic<Start>{});
        static_for<Start + 1, End>(static_cast<F&&>(f));
    }
}

__device__ __forceinline__ float rlane(float v, int lane) {
    return __int_as_float(__builtin_amdgcn_readlane(__float_as_int(v), lane));
}

__device__ __forceinline__ float frcp(float x) {
#if __has_builtin(__builtin_amdgcn_rcpf)
    return __builtin_amdgcn_rcpf(x);   // ~1 ulp; plenty vs 2e-3 abs threshold
#else
    return 1.0f / x;
#endif
}

__device__ __forceinline__ v2f fma2(v2f a, v2f b, v2f c) {
#if __has_builtin(__builtin_elementwise_fma)
    return __builtin_elementwise_fma(a, b, c);   // -> v_pk_fma_f32
#else
    v2f r; r.x = fmaf(a.x, b.x, c.x); r.y = fmaf(a.y, b.y, c.y); return r;
#endif
}

__global__ __launch_bounds__(256) void minvar_kernel(const float* __restrict__ sigma,
                                                     float* __restrict__ out,
                                                     int batch) {
    // [wave][panel parity][ m*8 + c*2 + par ] : u_c[2m+par]
    __shared__ float pb[4][2][2 * NN * 4 / 2];   // 4 waves x 2 x 256 floats = 8 KB

    const int lane = threadIdx.x & 63;
    const int wid  = threadIdx.x >> 6;     // 4 waves/block, 1 matrix each
    const int bid  = blockIdx.x * 4 + wid;
    if (bid >= batch) return;              // no barriers anywhere -> safe

    const float* __restrict__ p = sigma + (size_t)bid * (NN * NN) + (size_t)lane * NN;

    // lane i's row as 32 float2 pairs (all indices compile-time -> VGPRs)
    v2f r[NN / 2];
    static_for<0, NN / 4>([&](auto j4c) {
        constexpr int j4 = decltype(j4c)::value;
        v4f v = reinterpret_cast<const v4f*>(p)[j4];
        r[2 * j4 + 0] = v2f{v.x, v.y};
        r[2 * j4 + 1] = v2f{v.z, v.w};
    });

    float b = 1.0f;                        // RHS: ones
    float d = 1.0f;                        // my diagonal pivot (set at my step)
    const int wbase = (lane >> 1) * 8 + (lane & 1);   // scatter-write index

    static_for<0, 16>([&](auto pc) {
        constexpr int P  = decltype(pc)::value;
        constexpr int k0 = 4 * P;
        constexpr int m0 = 2 * P;          // pair-slots m0, m0+1 are the panel
        float* __restrict__ wb = &pb[wid][P & 1][0];

        // ---- phase 1: in-panel Jordan elimination (readlane only) ----
        const float el0  = r[m0].x;                    // A[i][k0] (pre-panel)
        const float piv0 = rlane(el0, k0);
        d = (lane == k0) ? piv0 : d;
        const float nf0  = (lane != k0) ? (-el0 * frcp(piv0)) : 0.0f;
        b = fmaf(nf0, rlane(b, k0), b);
        const float u01 = rlane(r[m0].y,     k0);
        const float u02 = rlane(r[m0 + 1].x, k0);
        const float u03 = rlane(r[m0 + 1].y, k0);
        r[m0].y     = fmaf(nf0, u01, r[m0].y);
        r[m0 + 1].x = fmaf(nf0, u02, r[m0 + 1].x);
        r[m0 + 1].y = fmaf(nf0, u03, r[m0 + 1].y);

        const float el1  = r[m0].y;                    // A[i][k0+1] after c0
        const float piv1 = rlane(el1, k0 + 1);
        d = (lane == k0 + 1) ? piv1 : d;
        const float nf1  = (lane != k0 + 1) ? (-el1 * frcp(piv1)) : 0.0f;
        b = fmaf(nf1, rlane(b, k0 + 1), b);
        const float u12 = rlane(r[m0 + 1].x, k0 + 1);
        const float u13 = rlane(r[m0 + 1].y, k0 + 1);
        r[m0 + 1].x = fmaf(nf1, u12, r[m0 + 1].x);
        r[m0 + 1].y = fmaf(nf1, u13, r[m0 + 1].y);

        const float el2  = r[m0 + 1].x;                // A[i][k0+2] after c0,c1
        const float piv2 = rlane(el2, k0 + 2);
        d = (lane == k0 + 2) ? piv2 : d;
        const float nf2  = (lane != k0 + 2) ? (-el2 * frcp(piv2)) : 0.0f;
        b = fmaf(nf2, rlane(b, k0 + 2), b);
        const float u23 = rlane(r[m0 + 1].y, k0 + 2);
        r[m0 + 1].y = fmaf(nf2, u23, r[m0 + 1].y);

        const float el3  = r[m0 + 1].y;                // A[i][k0+3] after c0..c2
        const float piv3 = rlane(el3, k0 + 3);
        d = (lane == k0 + 3) ? piv3 : d;
        const float nf3  = (lane != k0 + 3) ? (-el3 * frcp(piv3)) : 0.0f;
        b = fmaf(nf3, rlane(b, k0 + 3), b);

        if constexpr (P < 15) {
            // ---- phase 2: publish the 4 eliminated columns (transposed) ----
            wb[wbase + 0] = el0;
            wb[wbase + 2] = el1;
            wb[wbase + 4] = el2;
            wb[wbase + 6] = el3;

            // ---- phase 3: rank-4 Jordan update of ALL lanes' trailing slots ----
            const v2f n0 = v2f{nf0, nf0}, n1 = v2f{nf1, nf1};
            const v2f n2 = v2f{nf2, nf2}, n3 = v2f{nf3, nf3};
            static_for<m0 + 2, NN / 2>([&](auto mc) {
                constexpr int m = decltype(mc)::value;
                const v4f lo = *reinterpret_cast<const v4f*>(wb + 8 * m);     // u0,u1 pairs
                const v4f hi = *reinterpret_cast<const v4f*>(wb + 8 * m + 4); // u2,u3 pairs
                v2f acc = r[m];
                acc = fma2(n0, v2f{lo.x, lo.y}, acc);
                acc = fma2(n1, v2f{lo.z, lo.w}, acc);
                acc = fma2(n2, v2f{hi.x, hi.y}, acc);
                acc = fma2(n3, v2f{hi.z, hi.w}, acc);
                r[m] = acc;
            });
        }
    });

    // ---- Jordan epilogue: z = b / d, then normalize w = z / sum(z) ----
    const float z = b * frcp(d);
    float tot = z;
    #pragma unroll
    for (int off = 32; off >= 1; off >>= 1)
        tot += __shfl_xor(tot, off, 64);

    out[(size_t)bid * NN + lane] = z * frcp(tot);
}

extern "C" void kernel_launch(void* const* d_in, const int* in_sizes, int n_in,
                              void* d_out, int out_size, void* d_ws, size_t ws_size,
                              hipStream_t stream) {
    const float* sigma = (const float*)d_in[0];
    float* out = (float*)d_out;
    const int batch  = in_sizes[0] / (NN * NN);   // 8192
    const int blocks = (batch + 3) / 4;           // 4 matrices per 256-thr block
    minvar_kernel<<<blocks, 256, 0, stream>>>(sigma, out, batch);
}

// Round 10
// 209.713 us; speedup vs baseline: 1.0067x; 1.0067x over previous
//
#include <hip/hip_runtime.h>

// MinVarianceWeightsLayer: for each of B SPD 64x64 fp32 matrices S,
// solve S z = 1, output w = z / sum(z) as [B, 64, 1] fp32.
//
// ROUND-10: r9's rank-4 panel Gauss-Jordan, DS-pipe edition.
// r9 evidence: SQ_LDS_BANK_CONFLICT = 2.95M = exactly 6 extra cyc on each of
// the 491K publish writes (stride-8 scatter -> 8-way bank alias), and DS pipe
// ~60% busy vs VALU 30% -> DS is the limiting pipe.
// Fixes: (1) per-column layout pb[c][64] -> publish writes are stride-1
// (2 lanes/bank = free); (2) reads become paired ds_read2_b64 (same 2 DS
// instrs per slot as b128, offsets {m,32+m}/{64+m,96+m} in 8B units from one
// uniform base); (3) EARLY publish: each column written the moment phase 1
// produces it (per-wave DS is in-order; parity double-buffer kept) so the
// remaining phase-1 work hides the write->read round-trip.
// One wave per matrix, NO barriers.

#define NN 64

typedef float v2f __attribute__((ext_vector_type(2)));
typedef float v4f __attribute__((ext_vector_type(4)));

template <int I> struct ic { static constexpr int value = I; };

template <int Start, int End, typename F>
__device__ __forceinline__ void static_for(F&& f) {
    if constexpr (Start < End) {
        f(ic<Start>{});
        static_for<Start + 1, End>(static_cast<F&&>(f));
    }
}

__device__ __forceinline__ float rlane(float v, int lane) {
    return __int_as_float(__builtin_amdgcn_readlane(__float_as_int(v), lane));
}

__device__ __forceinline__ float frcp(float x) {
#if __has_builtin(__builtin_amdgcn_rcpf)
    return __builtin_amdgcn_rcpf(x);   // ~1 ulp; plenty vs 2e-3 abs threshold
#else
    return 1.0f / x;
#endif
}

__device__ __forceinline__ v2f fma2(v2f a, v2f b, v2f c) {
#if __has_builtin(__builtin_elementwise_fma)
    return __builtin_elementwise_fma(a, b, c);   // -> v_pk_fma_f32
#else
    v2f r; r.x = fmaf(a.x, b.x, c.x); r.y = fmaf(a.y, b.y, c.y); return r;
#endif
}

__global__ __launch_bounds__(256) void minvar_kernel(const float* __restrict__ sigma,
                                                     float* __restrict__ out,
                                                     int batch) {
    // [wave][panel parity][column c][row j] -- stride-1 writes, uniform reads
    __shared__ float pb[4][2][4][NN];    // 4 x 2 x 4 x 64 x 4B = 8 KB

    const int lane = threadIdx.x & 63;
    const int wid  = threadIdx.x >> 6;     // 4 waves/block, 1 matrix each
    const int bid  = blockIdx.x * 4 + wid;
    if (bid >= batch) return;              // no barriers anywhere -> safe

    const float* __restrict__ p = sigma + (size_t)bid * (NN * NN) + (size_t)lane * NN;

    // lane i's row as 32 float2 pairs (all indices compile-time -> VGPRs)
    v2f r[NN / 2];
    static_for<0, NN / 4>([&](auto j4c) {
        constexpr int j4 = decltype(j4c)::value;
        v4f v = reinterpret_cast<const v4f*>(p)[j4];
        r[2 * j4 + 0] = v2f{v.x, v.y};
        r[2 * j4 + 1] = v2f{v.z, v.w};
    });

    float b = 1.0f;                        // RHS: ones
    float d = 1.0f;                        // my diagonal pivot (set at my step)

    static_for<0, 16>([&](auto pc) {
        constexpr int P  = decltype(pc)::value;
        constexpr int k0 = 4 * P;
        constexpr int m0 = 2 * P;          // pair-slots m0, m0+1 are the panel
        float* __restrict__ wb = &pb[wid][P & 1][0][0];

        // ---- phase 1: in-panel Jordan elimination, EARLY per-column publish
        const float el0  = r[m0].x;                    // A[i][k0] (pre-panel)
        if constexpr (P < 15) wb[0 * NN + lane] = el0; // stride-1: conflict-free
        const float piv0 = rlane(el0, k0);
        d = (lane == k0) ? piv0 : d;
        const float nf0  = (lane != k0) ? (-el0 * frcp(piv0)) : 0.0f;
        b = fmaf(nf0, rlane(b, k0), b);
        const float u01 = rlane(r[m0].y,     k0);
        const float u02 = rlane(r[m0 + 1].x, k0);
        const float u03 = rlane(r[m0 + 1].y, k0);
        r[m0].y     = fmaf(nf0, u01, r[m0].y);
        r[m0 + 1].x = fmaf(nf0, u02, r[m0 + 1].x);
        r[m0 + 1].y = fmaf(nf0, u03, r[m0 + 1].y);

        const float el1  = r[m0].y;                    // A[i][k0+1] after c0
        if constexpr (P < 15) wb[1 * NN + lane] = el1;
        const float piv1 = rlane(el1, k0 + 1);
        d = (lane == k0 + 1) ? piv1 : d;
        const float nf1  = (lane != k0 + 1) ? (-el1 * frcp(piv1)) : 0.0f;
        b = fmaf(nf1, rlane(b, k0 + 1), b);
        const float u12 = rlane(r[m0 + 1].x, k0 + 1);
        const float u13 = rlane(r[m0 + 1].y, k0 + 1);
        r[m0 + 1].x = fmaf(nf1, u12, r[m0 + 1].x);
        r[m0 + 1].y = fmaf(nf1, u13, r[m0 + 1].y);

        const float el2  = r[m0 + 1].x;                // A[i][k0+2] after c0,c1
        if constexpr (P < 15) wb[2 * NN + lane] = el2;
        const float piv2 = rlane(el2, k0 + 2);
        d = (lane == k0 + 2) ? piv2 : d;
        const float nf2  = (lane != k0 + 2) ? (-el2 * frcp(piv2)) : 0.0f;
        b = fmaf(nf2, rlane(b, k0 + 2), b);
        const float u23 = rlane(r[m0 + 1].y, k0 + 2);
        r[m0 + 1].y = fmaf(nf2, u23, r[m0 + 1].y);

        const float el3  = r[m0 + 1].y;                // A[i][k0+3] after c0..c2
        if constexpr (P < 15) wb[3 * NN + lane] = el3;
        const float piv3 = rlane(el3, k0 + 3);
        d = (lane == k0 + 3) ? piv3 : d;
        const float nf3  = (lane != k0 + 3) ? (-el3 * frcp(piv3)) : 0.0f;
        b = fmaf(nf3, rlane(b, k0 + 3), b);

        if constexpr (P < 15) {
            // ---- phase 3: rank-4 Jordan update of ALL lanes' trailing slots.
            // Per slot: 4 adjacent v2f loads at byte offsets
            // {8m, 256+8m, 512+8m, 768+8m} from the uniform base wb ->
            // backend pairs them into 2x ds_read2_b64 (uniform broadcast).
            const v2f n0 = v2f{nf0, nf0}, n1 = v2f{nf1, nf1};
            const v2f n2 = v2f{nf2, nf2}, n3 = v2f{nf3, nf3};
            static_for<m0 + 2, NN / 2>([&](auto mc) {
                constexpr int m = decltype(mc)::value;
                const v2f u0 = *reinterpret_cast<const v2f*>(wb + 0 * NN + 2 * m);
                const v2f u1 = *reinterpret_cast<const v2f*>(wb + 1 * NN + 2 * m);
                const v2f u2 = *reinterpret_cast<const v2f*>(wb + 2 * NN + 2 * m);
                const v2f u3 = *reinterpret_cast<const v2f*>(wb + 3 * NN + 2 * m);
                v2f acc = r[m];
                acc = fma2(n0, u0, acc);
                acc = fma2(n1, u1, acc);
                acc = fma2(n2, u2, acc);
                acc = fma2(n3, u3, acc);
                r[m] = acc;
            });
        }
    });

    // ---- Jordan epilogue: z = b / d, then normalize w = z / sum(z) ----
    const float z = b * frcp(d);
    float tot = z;
    #pragma unroll
    for (int off = 32; off >= 1; off >>= 1)
        tot += __shfl_xor(tot, off, 64);

    out[(size_t)bid * NN + lane] = z * frcp(tot);
}

extern "C" void kernel_launch(void* const* d_in, const int* in_sizes, int n_in,
                              void* d_out, int out_size, void* d_ws, size_t ws_size,
                              hipStream_t stream) {
    const float* sigma = (const float*)d_in[0];
    float* out = (float*)d_out;
    const int batch  = in_sizes[0] / (NN * NN);   // 8192
    const int blocks = (batch + 3) / 4;           // 4 matrices per 256-thr block
    minvar_kernel<<<blocks, 256, 0, stream>>>(sigma, out, batch);
}

// Round 11
// 209.712 us; speedup vs baseline: 1.0067x; 1.0000x over previous
//
#include <hip/hip_runtime.h>

// MinVarianceWeightsLayer: for each of B SPD 64x64 fp32 matrices S,
// solve S z = 1, output w = z / sum(z) as [B, 64, 1] fp32.
//
// ROUND-11: dual-pipe broadcast. Evidence r4-r10: every variant converges to
// ~80us because the ~2K-element/wave broadcast volume runs through ONE pipe
// at ~10cyc/unit -- r4 all-readlane (VALU 65%), r10 all-LDS (DS-pipe ~full,
// VALU 30%). DS instr count is floored (16B/instr -> 480). Fix: split each
// rank-4 slot's 4 column-pairs across BOTH issue pipes:
//   u0 -> 2 v_readlane from the register-resident el0 (symmetry: u0[j] =
//         lane j's el0; no LDS involved)
//   u1,u2,u3 -> LDS uniform b64 reads (publish only el1..el3)
// Per-CU: DS ~360 instr/wave, VALU ~(480rl + fma + phase1) -- balanced.
// One wave per matrix, NO barriers; parity double-buffer; stride-1 writes.

#define NN 64

typedef float v2f __attribute__((ext_vector_type(2)));
typedef float v4f __attribute__((ext_vector_type(4)));

template <int I> struct ic { static constexpr int value = I; };

template <int Start, int End, typename F>
__device__ __forceinline__ void static_for(F&& f) {
    if constexpr (Start < End) {
        f(ic<Start>{});
        static_for<Start + 1, End>(static_cast<F&&>(f));
    }
}

__device__ __forceinline__ float rlane(float v, int lane) {
    return __int_as_float(__builtin_amdgcn_readlane(__float_as_int(v), lane));
}

__device__ __forceinline__ float frcp(float x) {
#if __has_builtin(__builtin_amdgcn_rcpf)
    return __builtin_amdgcn_rcpf(x);   // ~1 ulp; plenty vs 2e-3 abs threshold
#else
    return 1.0f / x;
#endif
}

__device__ __forceinline__ v2f fma2(v2f a, v2f b, v2f c) {
#if __has_builtin(__builtin_elementwise_fma)
    return __builtin_elementwise_fma(a, b, c);   // -> v_pk_fma_f32
#else
    v2f r; r.x = fmaf(a.x, b.x, c.x); r.y = fmaf(a.y, b.y, c.y); return r;
#endif
}

__global__ __launch_bounds__(256) void minvar_kernel(const float* __restrict__ sigma,
                                                     float* __restrict__ out,
                                                     int batch) {
    // [wave][panel parity][column c-1 (c=1..3)][row j] -- col 0 rides readlane
    __shared__ float pb[4][2][3][NN];    // 4 x 2 x 3 x 64 x 4B = 6 KB

    const int lane = threadIdx.x & 63;
    const int wid  = threadIdx.x >> 6;     // 4 waves/block, 1 matrix each
    const int bid  = blockIdx.x * 4 + wid;
    if (bid >= batch) return;              // no barriers anywhere -> safe

    const float* __restrict__ p = sigma + (size_t)bid * (NN * NN) + (size_t)lane * NN;

    // lane i's row as 32 float2 pairs (all indices compile-time -> VGPRs)
    v2f r[NN / 2];
    static_for<0, NN / 4>([&](auto j4c) {
        constexpr int j4 = decltype(j4c)::value;
        v4f v = reinterpret_cast<const v4f*>(p)[j4];
        r[2 * j4 + 0] = v2f{v.x, v.y};
        r[2 * j4 + 1] = v2f{v.z, v.w};
    });

    float b = 1.0f;                        // RHS: ones
    float d = 1.0f;                        // my diagonal pivot (set at my step)

    static_for<0, 16>([&](auto pc) {
        constexpr int P  = decltype(pc)::value;
        constexpr int k0 = 4 * P;
        constexpr int m0 = 2 * P;          // pair-slots m0, m0+1 are the panel
        float* __restrict__ wb = &pb[wid][P & 1][0][0];

        // ---- phase 1: in-panel Jordan elimination; publish el1..el3 early.
        const float el0  = r[m0].x;                    // stays in registers
        const float piv0 = rlane(el0, k0);
        d = (lane == k0) ? piv0 : d;
        const float nf0  = (lane != k0) ? (-el0 * frcp(piv0)) : 0.0f;
        b = fmaf(nf0, rlane(b, k0), b);
        const float u01 = rlane(r[m0].y,     k0);
        const float u02 = rlane(r[m0 + 1].x, k0);
        const float u03 = rlane(r[m0 + 1].y, k0);
        r[m0].y     = fmaf(nf0, u01, r[m0].y);
        r[m0 + 1].x = fmaf(nf0, u02, r[m0 + 1].x);
        r[m0 + 1].y = fmaf(nf0, u03, r[m0 + 1].y);

        const float el1  = r[m0].y;                    // A[i][k0+1] after c0
        if constexpr (P < 15) wb[0 * NN + lane] = el1; // stride-1: conflict-free
        const float piv1 = rlane(el1, k0 + 1);
        d = (lane == k0 + 1) ? piv1 : d;
        const float nf1  = (lane != k0 + 1) ? (-el1 * frcp(piv1)) : 0.0f;
        b = fmaf(nf1, rlane(b, k0 + 1), b);
        const float u12 = rlane(r[m0 + 1].x, k0 + 1);
        const float u13 = rlane(r[m0 + 1].y, k0 + 1);
        r[m0 + 1].x = fmaf(nf1, u12, r[m0 + 1].x);
        r[m0 + 1].y = fmaf(nf1, u13, r[m0 + 1].y);

        const float el2  = r[m0 + 1].x;                // A[i][k0+2] after c0,c1
        if constexpr (P < 15) wb[1 * NN + lane] = el2;
        const float piv2 = rlane(el2, k0 + 2);
        d = (lane == k0 + 2) ? piv2 : d;
        const float nf2  = (lane != k0 + 2) ? (-el2 * frcp(piv2)) : 0.0f;
        b = fmaf(nf2, rlane(b, k0 + 2), b);
        const float u23 = rlane(r[m0 + 1].y, k0 + 2);
        r[m0 + 1].y = fmaf(nf2, u23, r[m0 + 1].y);

        const float el3  = r[m0 + 1].y;                // A[i][k0+3] after c0..c2
        if constexpr (P < 15) wb[2 * NN + lane] = el3;
        const float piv3 = rlane(el3, k0 + 3);
        d = (lane == k0 + 3) ? piv3 : d;
        const float nf3  = (lane != k0 + 3) ? (-el3 * frcp(piv3)) : 0.0f;
        b = fmaf(nf3, rlane(b, k0 + 3), b);

        if constexpr (P < 15) {
            // ---- phase 3: rank-4 Jordan update; u0 on the VALU pipe
            // (readlane from el0), u1..u3 on the DS pipe (uniform b64 reads,
            // fusable to ds_read2_b64 offsets {m,64+m}/{128+m}).
            const v2f n0 = v2f{nf0, nf0}, n1 = v2f{nf1, nf1};
            const v2f n2 = v2f{nf2, nf2}, n3 = v2f{nf3, nf3};
            static_for<m0 + 2, NN / 2>([&](auto mc) {
                constexpr int m = decltype(mc)::value;
                const v2f u1 = *reinterpret_cast<const v2f*>(wb + 0 * NN + 2 * m);
                const v2f u2 = *reinterpret_cast<const v2f*>(wb + 1 * NN + 2 * m);
                const v2f u3 = *reinterpret_cast<const v2f*>(wb + 2 * NN + 2 * m);
                const v2f u0 = v2f{rlane(el0, 2 * m), rlane(el0, 2 * m + 1)};
                v2f acc = r[m];
                acc = fma2(n0, u0, acc);
                acc = fma2(n1, u1, acc);
                acc = fma2(n2, u2, acc);
                acc = fma2(n3, u3, acc);
                r[m] = acc;
            });
        }
    });

    // ---- Jordan epilogue: z = b / d, then normalize w = z / sum(z) ----
    const float z = b * frcp(d);
    float tot = z;
    #pragma unroll
    for (int off = 32; off >= 1; off >>= 1)
        tot += __shfl_xor(tot, off, 64);

    out[(size_t)bid * NN + lane] = z * frcp(tot);
}

extern "C" void kernel_launch(void* const* d_in, const int* in_sizes, int n_in,
                              void* d_out, int out_size, void* d_ws, size_t ws_size,
                              hipStream_t stream) {
    const float* sigma = (const float*)d_in[0];
    float* out = (float*)d_out;
    const int batch  = in_sizes[0] / (NN * NN);   // 8192
    const int blocks = (batch + 3) / 4;           // 4 matrices per 256-thr block
    minvar_kernel<<<blocks, 256, 0, stream>>>(sigma, out, batch);
}